// Round 3
// baseline (949.038 us; speedup 1.0000x reference)
//
#include <hip/hip_runtime.h>

#define N_USERS 100000
#define N_ITEMS 50000
#define N_NODES 150000
#define D 64
#define NNZ 2000000
#define BATCH 256
#define POP_BINS 10

#define NB_SCAN 586   // ceil(150000/256)

// bucketed scatter params
#define BSHIFT 10
#define NBUCK 147          // ceil(150000/1024)
#define P1_EPB 4096        // edges per block in pass 1
#define P1_BLOCKS 489      // ceil(NNZ/P1_EPB)

// ---------------- init: emb concat -> bufA, Oacc = 0.25*emb, zero counts ----
__global__ __launch_bounds__(256) void k_init(const float* __restrict__ ue,
                                              const float* __restrict__ ie,
                                              float* __restrict__ bufA,
                                              float* __restrict__ Oacc,
                                              int* __restrict__ counts) {
  int idx = blockIdx.x * 256 + threadIdx.x;
  if (idx < N_NODES * D) {
    float e = (idx < N_USERS * D) ? ue[idx] : ie[idx - N_USERS * D];
    bufA[idx] = e;
    Oacc[idx] = 0.25f * e;
  }
  if (idx < N_NODES) counts[idx] = 0;
}

// ---------------- CSR build ----------------
__global__ __launch_bounds__(256) void k_count(const int* __restrict__ rows,
                                               int* __restrict__ counts) {
  int e = blockIdx.x * 256 + threadIdx.x;
  if (e < NNZ) atomicAdd(&counts[rows[e]], 1);
}

__global__ __launch_bounds__(256) void k_scan1(const int* __restrict__ in,
                                               int* __restrict__ out,
                                               int* __restrict__ bsums, int n) {
  __shared__ int s[256];
  int t = threadIdx.x;
  int g = blockIdx.x * 256 + t;
  int v = (g < n) ? in[g] : 0;
  s[t] = v;
  __syncthreads();
  for (int off = 1; off < 256; off <<= 1) {
    int x = (t >= off) ? s[t - off] : 0;
    __syncthreads();
    s[t] += x;
    __syncthreads();
  }
  if (g < n) out[g] = s[t] - v;  // exclusive
  if (t == 255) bsums[blockIdx.x] = s[t];
}

__global__ __launch_bounds__(1024) void k_scan2(int* __restrict__ bs, int nb) {
  __shared__ int s[1024];
  int t = threadIdx.x;
  int v = (t < nb) ? bs[t] : 0;
  s[t] = v;
  __syncthreads();
  for (int off = 1; off < 1024; off <<= 1) {
    int x = (t >= off) ? s[t - off] : 0;
    __syncthreads();
    s[t] += x;
    __syncthreads();
  }
  if (t < nb) bs[t] = s[t] - v;  // exclusive
}

__global__ __launch_bounds__(256) void k_scan3(int* __restrict__ rowptr,
                                               int* __restrict__ cursor,
                                               const int* __restrict__ bsums, int n) {
  int g = blockIdx.x * 256 + threadIdx.x;
  if (g < n) {
    int v = rowptr[g] + bsums[blockIdx.x];
    rowptr[g] = v;
    cursor[g] = v;
  }
  if (g == 0) rowptr[n] = NNZ;
}

__global__ __launch_bounds__(256) void k_binit(const int* __restrict__ rowptr,
                                               int* __restrict__ bcur) {
  int t = threadIdx.x;
  if (t < NBUCK) bcur[t] = rowptr[t << BSHIFT];
}

// ---------------- pass 1: bucket edges into staging (clustered writes) ------
__global__ __launch_bounds__(256) void k_p1(const int* __restrict__ rows,
                                            const int* __restrict__ cols,
                                            const float* __restrict__ vals,
                                            int* __restrict__ bcur,
                                            uint2* __restrict__ gstage) {
  __shared__ int cnt[NBUCK];
  __shared__ int gbase[NBUCK];
  int t = threadIdx.x;
  if (t < NBUCK) cnt[t] = 0;
  __syncthreads();
  int base = blockIdx.x * P1_EPB;
  unsigned key[16]; float val[16]; int meta[16];
#pragma unroll
  for (int i = 0; i < 16; i++) {
    int e = base + i * 256 + t;
    meta[i] = -1;
    if (e < NNZ) {
      int r = rows[e];
      int b = r >> BSHIFT;
      int lr = r - (b << BSHIFT);
      key[i] = ((unsigned)lr << 18) | (unsigned)cols[e];
      val[i] = vals[e];
      int rank = atomicAdd(&cnt[b], 1);
      meta[i] = (b << 13) | rank;   // rank < 4096 fits in 13 bits
    }
  }
  __syncthreads();
  if (t < NBUCK) gbase[t] = atomicAdd(&bcur[t], cnt[t]);
  __syncthreads();
#pragma unroll
  for (int i = 0; i < 16; i++) {
    if (meta[i] >= 0) {
      int b = meta[i] >> 13, rank = meta[i] & 8191;
      gstage[gbase[b] + rank] = make_uint2(key[i], __float_as_uint(val[i]));
    }
  }
}

// ---------------- pass 2: bucket-local scatter to CSR position --------------
__global__ __launch_bounds__(256) void k_p2(const int* __restrict__ rowptr,
                                            const uint2* __restrict__ gstage,
                                            int* __restrict__ cursor,
                                            uint2* __restrict__ epack) {
  int b = blockIdx.x;
  int s = rowptr[b << BSHIFT];
  int rend = (b + 1) << BSHIFT;
  if (rend > N_NODES) rend = N_NODES;
  int e = rowptr[rend];
  int half = (e - s) >> 1;
  int lo = blockIdx.y ? (s + half) : s;
  int hi = blockIdx.y ? e : (s + half);
  int rowbase = b << BSHIFT;
  for (int j = lo + threadIdx.x; j < hi; j += 256) {
    uint2 ed = gstage[j];
    int row = rowbase + (int)(ed.x >> 18);
    int col = (int)(ed.x & 0x3FFFFu);
    int pos = atomicAdd(&cursor[row], 1);
    epack[pos] = make_uint2((unsigned)col, ed.y);
  }
}

// ---------------- SPMM: one wave per row, scalar edge loads ----------------
__global__ __launch_bounds__(256) void k_spmm(const int* __restrict__ rowptr,
                                              const uint2* __restrict__ epack,
                                              const float* __restrict__ Ein,
                                              float* __restrict__ Eout,
                                              float* __restrict__ Oacc) {
  int wave = blockIdx.x * 4 + (threadIdx.x >> 6);
  int row = __builtin_amdgcn_readfirstlane(wave);  // force uniform -> s_loads
  if (row >= N_NODES) return;
  int lane = threadIdx.x & 63;
  int beg = rowptr[row];
  int end = rowptr[row + 1];
  float acc0 = 0.f, acc1 = 0.f;
  int j = beg;
  for (; j + 3 < end; j += 4) {
    uint2 e0 = epack[j], e1 = epack[j + 1], e2 = epack[j + 2], e3 = epack[j + 3];
    acc0 += __uint_as_float(e0.y) * Ein[(int)e0.x * D + lane];
    acc1 += __uint_as_float(e1.y) * Ein[(int)e1.x * D + lane];
    acc0 += __uint_as_float(e2.y) * Ein[(int)e2.x * D + lane];
    acc1 += __uint_as_float(e3.y) * Ein[(int)e3.x * D + lane];
  }
  for (; j < end; ++j) {
    uint2 e0 = epack[j];
    acc0 += __uint_as_float(e0.y) * Ein[(int)e0.x * D + lane];
  }
  float acc = acc0 + acc1;
  int o = row * D + lane;
  Eout[o] = acc;
  Oacc[o] += 0.25f * acc;
}

// ---------------- weight transpose: uW1T[64][64] (for k_user) ---------------
__global__ __launch_bounds__(256) void k_wt(const float* __restrict__ uW1,
                                            float* __restrict__ WT) {
  int t = blockIdx.x * 256 + threadIdx.x;
  if (t < 4096) {
    int o = t >> 6, k = t & 63;
    WT[t] = uW1[k * 64 + o];
  }
}

// ---------------- user MLP: thread per user, scalar weights, write U^T ------
__global__ __launch_bounds__(64) void k_user(const float* __restrict__ Oacc,
                                             const int* __restrict__ users,
                                             const float* __restrict__ ubias,
                                             const float* __restrict__ uW1T,
                                             const float* __restrict__ ub1,
                                             const float* __restrict__ uW2,
                                             const float* __restrict__ ub2,
                                             float* __restrict__ Ut) {
  int b = blockIdx.x * 64 + threadIdx.x;
  int u = users[b];
  float x[64];
  const float4* xr = (const float4*)(Oacc + (size_t)u * 64);
#pragma unroll
  for (int q = 0; q < 16; q++) {
    float4 t4 = xr[q];
    x[4 * q] = t4.x; x[4 * q + 1] = t4.y; x[4 * q + 2] = t4.z; x[4 * q + 3] = t4.w;
  }
  float acc[64];
#pragma unroll
  for (int o2 = 0; o2 < 64; o2++) acc[o2] = ub2[o2];
#pragma unroll 1
  for (int o = 0; o < 64; o++) {
    const float* w = uW1T + o * 64;
    float a0 = ub1[o], a1 = 0.f, a2 = 0.f, a3 = 0.f;
#pragma unroll
    for (int k = 0; k < 64; k += 4) {
      a0 += x[k] * w[k]; a1 += x[k + 1] * w[k + 1];
      a2 += x[k + 2] * w[k + 2]; a3 += x[k + 3] * w[k + 3];
    }
    float hv = a0 + a1 + a2 + a3;
    hv = hv > 0.f ? hv : 0.f;
    const float* w2 = uW2 + o * 64;
#pragma unroll
    for (int o2 = 0; o2 < 64; o2++) acc[o2] += hv * w2[o2];
  }
#pragma unroll 1
  for (int o2 = 0; o2 < 64; o2++) Ut[o2 * 256 + b] = acc[o2];
  Ut[64 * 256 + b] = ubias[u];  // BIAS_SCALE = 1.0
}

// ---------------- gate + item MLP fused: 64 items x 4 slices per block ------
// tid = s*64 + li; s = hidden/output slice (wave), li = local item (lane).
// Weights accessed k-major (original layout) -> wave-uniform s_load of 16
// contiguous floats; item data from LDS stride-65 (conflict-free).
__global__ __launch_bounds__(256) void k_gate(const float* __restrict__ Oacc,
                                              const float* __restrict__ pop,
                                              const int* __restrict__ bins,
                                              const float* __restrict__ gW1,
                                              const float* __restrict__ gb1,
                                              const float* __restrict__ gW2,
                                              const float* __restrict__ gb2,
                                              const float* __restrict__ iW1,
                                              const float* __restrict__ ib1,
                                              const float* __restrict__ iW2,
                                              const float* __restrict__ ib2,
                                              float* __restrict__ I) {
  __shared__ float Xs[64 * 65];
  __shared__ float Hs[64 * 65];
  __shared__ float Ps[POP_BINS * 65];
  __shared__ float Zp[4 * 64];
  int tid = threadIdx.x;
  int i0 = blockIdx.x * 64;
  for (int idx = tid; idx < POP_BINS * 64; idx += 256) {
    int b = idx >> 6, k = idx & 63;
    Ps[b * 65 + k] = pop[idx];
  }
  for (int idx = tid; idx < 64 * 64; idx += 256) {
    int r = idx >> 6, c = idx & 63;
    Xs[r * 65 + c] = (i0 + r < N_ITEMS) ? Oacc[(size_t)(N_USERS + i0 + r) * 64 + c] : 0.f;
  }
  __syncthreads();
  int s = tid >> 6;
  int li = tid & 63;
  int item = i0 + li;
  int bin = (item < N_ITEMS) ? bins[item] : 0;
  const float* xrow = Xs + li * 65;
  const float* prow = Ps + bin * 65;
  // stage 1: gate hidden (o = s*16+oo), over concat[x, p] (128-dim)
  float h[16];
#pragma unroll
  for (int oo = 0; oo < 16; oo++) h[oo] = gb1[s * 16 + oo];
#pragma unroll 4
  for (int k = 0; k < 64; k++) {
    float xk = xrow[k];
    const float* w = gW1 + k * 64 + s * 16;
#pragma unroll
    for (int oo = 0; oo < 16; oo++) h[oo] += xk * w[oo];
  }
#pragma unroll 4
  for (int k = 0; k < 64; k++) {
    float pk = prow[k];
    const float* w = gW1 + (64 + k) * 64 + s * 16;
#pragma unroll
    for (int oo = 0; oo < 16; oo++) h[oo] += pk * w[oo];
  }
  float pz = 0.f;
#pragma unroll
  for (int oo = 0; oo < 16; oo++) {
    float hv = h[oo] > 0.f ? h[oo] : 0.f;
    pz += hv * gW2[s * 16 + oo];
  }
  Zp[s * 64 + li] = pz;
  __syncthreads();
  float ssum = gb2[0] + Zp[li] + Zp[64 + li] + Zp[128 + li] + Zp[192 + li];
  float z = 1.f / (1.f + expf(-ssum));
  // stage 3: x' = (1-z)x + z*p, item MLP layer 1 (16 neurons)
  float h2[16];
#pragma unroll
  for (int oo = 0; oo < 16; oo++) h2[oo] = ib1[s * 16 + oo];
#pragma unroll 4
  for (int k = 0; k < 64; k++) {
    float xk = (1.f - z) * xrow[k] + z * prow[k];
    const float* w = iW1 + k * 64 + s * 16;
#pragma unroll
    for (int oo = 0; oo < 16; oo++) h2[oo] += xk * w[oo];
  }
#pragma unroll
  for (int oo = 0; oo < 16; oo++) {
    float hv = h2[oo] > 0.f ? h2[oo] : 0.f;
    Hs[li * 65 + s * 16 + oo] = hv;
  }
  __syncthreads();
  // stage 4: item MLP layer 2 (16 outputs c = s*16+cc)
  float acc[16];
#pragma unroll
  for (int cc = 0; cc < 16; cc++) acc[cc] = ib2[s * 16 + cc];
#pragma unroll 4
  for (int o = 0; o < 64; o++) {
    float hv = Hs[li * 65 + o];
    const float* w = iW2 + o * 64 + s * 16;
#pragma unroll
    for (int cc = 0; cc < 16; cc++) acc[cc] += hv * w[cc];
  }
#pragma unroll
  for (int cc = 0; cc < 16; cc++) Xs[li * 65 + s * 16 + cc] = acc[cc];
  __syncthreads();
  for (int idx = tid; idx < 64 * 64; idx += 256) {
    int r = idx >> 6, c = idx & 63;
    if (i0 + r < N_ITEMS) I[(size_t)(i0 + r) * 64 + c] = Xs[r * 65 + c];
  }
}

// ---------------- scores: 128-item tile, 64-user strip per thread -----------
__global__ __launch_bounds__(256) void k_scores(const float* __restrict__ I,
                                                const float* __restrict__ Ut,
                                                const float* __restrict__ item_bias,
                                                float* __restrict__ out) {
  __shared__ float Is[128 * 65];
  int i0 = blockIdx.x * 128;
  int tid = threadIdx.x;
  for (int idx = tid; idx < 128 * 64; idx += 256) {
    int r = idx >> 6, c = idx & 63;
    Is[r * 65 + c] = (i0 + r < N_ITEMS) ? I[(size_t)(i0 + r) * 64 + c] : 0.f;
  }
  __syncthreads();
  int li = tid & 127;
  int uh = tid >> 7;  // which 64-user strip
  int i = i0 + li;
  bool valid = i < N_ITEMS;
  float ib = valid ? item_bias[i] : 0.f;
  float xr[64];
#pragma unroll
  for (int k = 0; k < 64; k++) xr[k] = Is[li * 65 + k];
  int bbase = blockIdx.y * 128 + uh * 64;
#pragma unroll 1
  for (int b0 = 0; b0 < 64; b0 += 8) {
    float acc[8];
#pragma unroll
    for (int jj = 0; jj < 8; jj++) acc[jj] = 0.f;
#pragma unroll
    for (int k = 0; k < 64; k++) {
      float iv = xr[k];
      const float* urow = Ut + k * 256 + bbase + b0;
#pragma unroll
      for (int jj = 0; jj < 8; jj++) acc[jj] += iv * urow[jj];
    }
    if (valid) {
#pragma unroll
      for (int jj = 0; jj < 8; jj++) {
        int b = bbase + b0 + jj;
        out[b * N_ITEMS + i] = acc[jj] + Ut[64 * 256 + b] + ib;
      }
    }
  }
}

extern "C" void kernel_launch(void* const* d_in, const int* in_sizes, int n_in,
                              void* d_out, int out_size, void* d_ws, size_t ws_size,
                              hipStream_t stream) {
  const float* user_emb  = (const float*)d_in[0];
  const float* item_emb  = (const float*)d_in[1];
  const float* user_bias = (const float*)d_in[2];
  const float* item_bias = (const float*)d_in[3];
  const float* pop_emb   = (const float*)d_in[4];
  const float* uW1 = (const float*)d_in[5];
  const float* ub1 = (const float*)d_in[6];
  const float* uW2 = (const float*)d_in[7];
  const float* ub2 = (const float*)d_in[8];
  const float* iW1 = (const float*)d_in[9];
  const float* ib1 = (const float*)d_in[10];
  const float* iW2 = (const float*)d_in[11];
  const float* ib2 = (const float*)d_in[12];
  const float* gW1 = (const float*)d_in[13];
  const float* gb1 = (const float*)d_in[14];
  const float* gW2 = (const float*)d_in[15];
  const float* gb2 = (const float*)d_in[16];
  const float* adj_vals = (const float*)d_in[17];
  const int* adj_rows = (const int*)d_in[18];
  const int* adj_cols = (const int*)d_in[19];
  const int* bins  = (const int*)d_in[20];
  const int* users = (const int*)d_in[21];
  float* out = (float*)d_out;

  // workspace layout (float offsets); total ~132.7 MB
  float* ws = (float*)d_ws;
  float* Oacc = ws;                    // 9,600,000
  float* bufA = ws + 9600000;          // 9,600,000
  float* bufB = ws + 19200000;         // 9,600,000 (gstage aliases this pre-SPMM)
  uint2* epack = (uint2*)(ws + 28800000);      // 2,000,000 * 8B
  int* rowptr = (int*)(ws + 32800000);         // 150,001
  int* cursor = (int*)(ws + 32960000);         // 150,000
  int* bsums  = (int*)(ws + 33120000);         // 1,024
  float* Ut   = ws + 33130000;                 // 65*256
  float* WT   = ws + 33150000;                 // 4,096 (uW1T)
  int* bcur   = (int*)(ws + 33170000);         // 147
  uint2* gstage = (uint2*)bufB;                // 2,000,000 * 8B, dead before SPMM L1
  const float* uW1T = WT;

  k_init<<<37500, 256, 0, stream>>>(user_emb, item_emb, bufA, Oacc, cursor);
  k_count<<<(NNZ + 255) / 256, 256, 0, stream>>>(adj_rows, cursor);
  k_scan1<<<NB_SCAN, 256, 0, stream>>>(cursor, rowptr, bsums, N_NODES);
  k_scan2<<<1, 1024, 0, stream>>>(bsums, NB_SCAN);
  k_scan3<<<NB_SCAN, 256, 0, stream>>>(rowptr, cursor, bsums, N_NODES);
  k_binit<<<1, 256, 0, stream>>>(rowptr, bcur);
  k_p1<<<P1_BLOCKS, 256, 0, stream>>>(adj_rows, adj_cols, adj_vals, bcur, gstage);
  k_p2<<<dim3(NBUCK, 2), 256, 0, stream>>>(rowptr, gstage, cursor, epack);

  k_spmm<<<37500, 256, 0, stream>>>(rowptr, epack, bufA, bufB, Oacc);
  k_spmm<<<37500, 256, 0, stream>>>(rowptr, epack, bufB, bufA, Oacc);
  k_spmm<<<37500, 256, 0, stream>>>(rowptr, epack, bufA, bufB, Oacc);

  k_wt<<<16, 256, 0, stream>>>(uW1, WT);
  k_user<<<4, 64, 0, stream>>>(Oacc, users, user_bias, uW1T, ub1, uW2, ub2, Ut);
  k_gate<<<782, 256, 0, stream>>>(Oacc, pop_emb, bins, gW1, gb1, gW2, gb2,
                                  iW1, ib1, iW2, ib2, bufA);
  k_scores<<<dim3(391, 2), 256, 0, stream>>>(bufA, Ut, item_bias, out);
}

// Round 4
// 834.821 us; speedup vs baseline: 1.1368x; 1.1368x over previous
//
#include <hip/hip_runtime.h>

#define N_USERS 100000
#define N_ITEMS 50000
#define N_NODES 150000
#define D 64
#define NNZ 2000000
#define BATCH 256
#define POP_BINS 10

#define NB_SCAN 586   // ceil(150000/256)

// bucketed scatter params
#define BSHIFT 10
#define NBUCK 147          // ceil(150000/1024)
#define P1_EPB 4096        // edges per block in pass 1
#define P1_BLOCKS 489      // ceil(NNZ/P1_EPB)

#define ST_P 130           // k_scores I-tile LDS pad (odd-ish stride, conflict-light)

// ---------------- init: emb concat -> bufA, Oacc = 0.25*emb, zero counts ----
__global__ __launch_bounds__(256) void k_init(const float* __restrict__ ue,
                                              const float* __restrict__ ie,
                                              float* __restrict__ bufA,
                                              float* __restrict__ Oacc,
                                              int* __restrict__ counts) {
  int idx = blockIdx.x * 256 + threadIdx.x;
  if (idx < N_NODES * D) {
    float e = (idx < N_USERS * D) ? ue[idx] : ie[idx - N_USERS * D];
    bufA[idx] = e;
    Oacc[idx] = 0.25f * e;
  }
  if (idx < N_NODES) counts[idx] = 0;
}

// ---------------- CSR build ----------------
__global__ __launch_bounds__(256) void k_count(const int* __restrict__ rows,
                                               int* __restrict__ counts) {
  int e = blockIdx.x * 256 + threadIdx.x;
  if (e < NNZ) atomicAdd(&counts[rows[e]], 1);
}

__global__ __launch_bounds__(256) void k_scan1(const int* __restrict__ in,
                                               int* __restrict__ out,
                                               int* __restrict__ bsums, int n) {
  __shared__ int s[256];
  int t = threadIdx.x;
  int g = blockIdx.x * 256 + t;
  int v = (g < n) ? in[g] : 0;
  s[t] = v;
  __syncthreads();
  for (int off = 1; off < 256; off <<= 1) {
    int x = (t >= off) ? s[t - off] : 0;
    __syncthreads();
    s[t] += x;
    __syncthreads();
  }
  if (g < n) out[g] = s[t] - v;  // exclusive
  if (t == 255) bsums[blockIdx.x] = s[t];
}

__global__ __launch_bounds__(1024) void k_scan2(int* __restrict__ bs, int nb) {
  __shared__ int s[1024];
  int t = threadIdx.x;
  int v = (t < nb) ? bs[t] : 0;
  s[t] = v;
  __syncthreads();
  for (int off = 1; off < 1024; off <<= 1) {
    int x = (t >= off) ? s[t - off] : 0;
    __syncthreads();
    s[t] += x;
    __syncthreads();
  }
  if (t < nb) bs[t] = s[t] - v;  // exclusive
}

__global__ __launch_bounds__(256) void k_scan3(int* __restrict__ rowptr,
                                               int* __restrict__ cursor,
                                               const int* __restrict__ bsums, int n) {
  int g = blockIdx.x * 256 + threadIdx.x;
  if (g < n) {
    int v = rowptr[g] + bsums[blockIdx.x];
    rowptr[g] = v;
    cursor[g] = v;
  }
  if (g == 0) rowptr[n] = NNZ;
}

__global__ __launch_bounds__(256) void k_binit(const int* __restrict__ rowptr,
                                               int* __restrict__ bcur) {
  int t = threadIdx.x;
  if (t < NBUCK) bcur[t] = rowptr[t << BSHIFT];
}

// ---------------- pass 1: bucket edges into staging (clustered writes) ------
__global__ __launch_bounds__(256) void k_p1(const int* __restrict__ rows,
                                            const int* __restrict__ cols,
                                            const float* __restrict__ vals,
                                            int* __restrict__ bcur,
                                            uint2* __restrict__ gstage) {
  __shared__ int cnt[NBUCK];
  __shared__ int gbase[NBUCK];
  int t = threadIdx.x;
  if (t < NBUCK) cnt[t] = 0;
  __syncthreads();
  int base = blockIdx.x * P1_EPB;
  unsigned key[16]; float val[16]; int meta[16];
#pragma unroll
  for (int i = 0; i < 16; i++) {
    int e = base + i * 256 + t;
    meta[i] = -1;
    if (e < NNZ) {
      int r = rows[e];
      int b = r >> BSHIFT;
      int lr = r - (b << BSHIFT);
      key[i] = ((unsigned)lr << 18) | (unsigned)cols[e];
      val[i] = vals[e];
      int rank = atomicAdd(&cnt[b], 1);
      meta[i] = (b << 13) | rank;   // rank < 4096 fits in 13 bits
    }
  }
  __syncthreads();
  if (t < NBUCK) gbase[t] = atomicAdd(&bcur[t], cnt[t]);
  __syncthreads();
#pragma unroll
  for (int i = 0; i < 16; i++) {
    if (meta[i] >= 0) {
      int b = meta[i] >> 13, rank = meta[i] & 8191;
      gstage[gbase[b] + rank] = make_uint2(key[i], __float_as_uint(val[i]));
    }
  }
}

// ---------------- pass 2: bucket-local scatter to CSR position --------------
__global__ __launch_bounds__(256) void k_p2(const int* __restrict__ rowptr,
                                            const uint2* __restrict__ gstage,
                                            int* __restrict__ cursor,
                                            uint2* __restrict__ epack) {
  int b = blockIdx.x;
  int s = rowptr[b << BSHIFT];
  int rend = (b + 1) << BSHIFT;
  if (rend > N_NODES) rend = N_NODES;
  int e = rowptr[rend];
  int half = (e - s) >> 1;
  int lo = blockIdx.y ? (s + half) : s;
  int hi = blockIdx.y ? e : (s + half);
  int rowbase = b << BSHIFT;
  for (int j = lo + threadIdx.x; j < hi; j += 256) {
    uint2 ed = gstage[j];
    int row = rowbase + (int)(ed.x >> 18);
    int col = (int)(ed.x & 0x3FFFFu);
    int pos = atomicAdd(&cursor[row], 1);
    epack[pos] = make_uint2((unsigned)col, ed.y);
  }
}

// ---------------- SPMM: one wave per row, scalar edge loads ----------------
__global__ __launch_bounds__(256) void k_spmm(const int* __restrict__ rowptr,
                                              const uint2* __restrict__ epack,
                                              const float* __restrict__ Ein,
                                              float* __restrict__ Eout,
                                              float* __restrict__ Oacc) {
  int wave = blockIdx.x * 4 + (threadIdx.x >> 6);
  int row = __builtin_amdgcn_readfirstlane(wave);  // force uniform -> s_loads
  if (row >= N_NODES) return;
  int lane = threadIdx.x & 63;
  int beg = rowptr[row];
  int end = rowptr[row + 1];
  float acc0 = 0.f, acc1 = 0.f;
  int j = beg;
  for (; j + 3 < end; j += 4) {
    uint2 e0 = epack[j], e1 = epack[j + 1], e2 = epack[j + 2], e3 = epack[j + 3];
    acc0 += __uint_as_float(e0.y) * Ein[(int)e0.x * D + lane];
    acc1 += __uint_as_float(e1.y) * Ein[(int)e1.x * D + lane];
    acc0 += __uint_as_float(e2.y) * Ein[(int)e2.x * D + lane];
    acc1 += __uint_as_float(e3.y) * Ein[(int)e3.x * D + lane];
  }
  for (; j < end; ++j) {
    uint2 e0 = epack[j];
    acc0 += __uint_as_float(e0.y) * Ein[(int)e0.x * D + lane];
  }
  float acc = acc0 + acc1;
  int o = row * D + lane;
  Eout[o] = acc;
  Oacc[o] += 0.25f * acc;
}

// ---------------- weight transpose: uW1T[64][64] (for k_user) ---------------
__global__ __launch_bounds__(256) void k_wt(const float* __restrict__ uW1,
                                            float* __restrict__ WT) {
  int t = blockIdx.x * 256 + threadIdx.x;
  if (t < 4096) {
    int o = t >> 6, k = t & 63;
    WT[t] = uW1[k * 64 + o];
  }
}

// ---------------- user MLP: thread per user, scalar weights, write U^T ------
__global__ __launch_bounds__(64) void k_user(const float* __restrict__ Oacc,
                                             const int* __restrict__ users,
                                             const float* __restrict__ ubias,
                                             const float* __restrict__ uW1T,
                                             const float* __restrict__ ub1,
                                             const float* __restrict__ uW2,
                                             const float* __restrict__ ub2,
                                             float* __restrict__ Ut) {
  int b = blockIdx.x * 64 + threadIdx.x;
  int u = users[b];
  float x[64];
  const float4* xr = (const float4*)(Oacc + (size_t)u * 64);
#pragma unroll
  for (int q = 0; q < 16; q++) {
    float4 t4 = xr[q];
    x[4 * q] = t4.x; x[4 * q + 1] = t4.y; x[4 * q + 2] = t4.z; x[4 * q + 3] = t4.w;
  }
  float acc[64];
#pragma unroll
  for (int o2 = 0; o2 < 64; o2++) acc[o2] = ub2[o2];
#pragma unroll 1
  for (int o = 0; o < 64; o++) {
    const float* w = uW1T + o * 64;
    float a0 = ub1[o], a1 = 0.f, a2 = 0.f, a3 = 0.f;
#pragma unroll
    for (int k = 0; k < 64; k += 4) {
      a0 += x[k] * w[k]; a1 += x[k + 1] * w[k + 1];
      a2 += x[k + 2] * w[k + 2]; a3 += x[k + 3] * w[k + 3];
    }
    float hv = a0 + a1 + a2 + a3;
    hv = hv > 0.f ? hv : 0.f;
    const float* w2 = uW2 + o * 64;
#pragma unroll
    for (int o2 = 0; o2 < 64; o2++) acc[o2] += hv * w2[o2];
  }
#pragma unroll 1
  for (int o2 = 0; o2 < 64; o2++) Ut[o2 * 256 + b] = acc[o2];
  Ut[64 * 256 + b] = ubias[u];  // BIAS_SCALE = 1.0
}

// ---------------- gate + item MLP fused: 64 items x 4 slices per block ------
__global__ __launch_bounds__(256) void k_gate(const float* __restrict__ Oacc,
                                              const float* __restrict__ pop,
                                              const int* __restrict__ bins,
                                              const float* __restrict__ gW1,
                                              const float* __restrict__ gb1,
                                              const float* __restrict__ gW2,
                                              const float* __restrict__ gb2,
                                              const float* __restrict__ iW1,
                                              const float* __restrict__ ib1,
                                              const float* __restrict__ iW2,
                                              const float* __restrict__ ib2,
                                              float* __restrict__ I) {
  __shared__ float Xs[64 * 65];
  __shared__ float Hs[64 * 65];
  __shared__ float Ps[POP_BINS * 65];
  __shared__ float Zp[4 * 64];
  int tid = threadIdx.x;
  int i0 = blockIdx.x * 64;
  for (int idx = tid; idx < POP_BINS * 64; idx += 256) {
    int b = idx >> 6, k = idx & 63;
    Ps[b * 65 + k] = pop[idx];
  }
  for (int idx = tid; idx < 64 * 64; idx += 256) {
    int r = idx >> 6, c = idx & 63;
    Xs[r * 65 + c] = (i0 + r < N_ITEMS) ? Oacc[(size_t)(N_USERS + i0 + r) * 64 + c] : 0.f;
  }
  __syncthreads();
  int s = tid >> 6;
  int li = tid & 63;
  int item = i0 + li;
  int bin = (item < N_ITEMS) ? bins[item] : 0;
  const float* xrow = Xs + li * 65;
  const float* prow = Ps + bin * 65;
  // stage 1: gate hidden (o = s*16+oo), over concat[x, p] (128-dim)
  float h[16];
#pragma unroll
  for (int oo = 0; oo < 16; oo++) h[oo] = gb1[s * 16 + oo];
#pragma unroll 4
  for (int k = 0; k < 64; k++) {
    float xk = xrow[k];
    const float* w = gW1 + k * 64 + s * 16;
#pragma unroll
    for (int oo = 0; oo < 16; oo++) h[oo] += xk * w[oo];
  }
#pragma unroll 4
  for (int k = 0; k < 64; k++) {
    float pk = prow[k];
    const float* w = gW1 + (64 + k) * 64 + s * 16;
#pragma unroll
    for (int oo = 0; oo < 16; oo++) h[oo] += pk * w[oo];
  }
  float pz = 0.f;
#pragma unroll
  for (int oo = 0; oo < 16; oo++) {
    float hv = h[oo] > 0.f ? h[oo] : 0.f;
    pz += hv * gW2[s * 16 + oo];
  }
  Zp[s * 64 + li] = pz;
  __syncthreads();
  float ssum = gb2[0] + Zp[li] + Zp[64 + li] + Zp[128 + li] + Zp[192 + li];
  float z = 1.f / (1.f + expf(-ssum));
  // stage 3: x' = (1-z)x + z*p, item MLP layer 1 (16 neurons)
  float h2[16];
#pragma unroll
  for (int oo = 0; oo < 16; oo++) h2[oo] = ib1[s * 16 + oo];
#pragma unroll 4
  for (int k = 0; k < 64; k++) {
    float xk = (1.f - z) * xrow[k] + z * prow[k];
    const float* w = iW1 + k * 64 + s * 16;
#pragma unroll
    for (int oo = 0; oo < 16; oo++) h2[oo] += xk * w[oo];
  }
#pragma unroll
  for (int oo = 0; oo < 16; oo++) {
    float hv = h2[oo] > 0.f ? h2[oo] : 0.f;
    Hs[li * 65 + s * 16 + oo] = hv;
  }
  __syncthreads();
  // stage 4: item MLP layer 2 (16 outputs c = s*16+cc)
  float acc[16];
#pragma unroll
  for (int cc = 0; cc < 16; cc++) acc[cc] = ib2[s * 16 + cc];
#pragma unroll 4
  for (int o = 0; o < 64; o++) {
    float hv = Hs[li * 65 + o];
    const float* w = iW2 + o * 64 + s * 16;
#pragma unroll
    for (int cc = 0; cc < 16; cc++) acc[cc] += hv * w[cc];
  }
#pragma unroll
  for (int cc = 0; cc < 16; cc++) Xs[li * 65 + s * 16 + cc] = acc[cc];
  __syncthreads();
  for (int idx = tid; idx < 64 * 64; idx += 256) {
    int r = idx >> 6, c = idx & 63;
    if (i0 + r < N_ITEMS) I[(size_t)(i0 + r) * 64 + c] = Xs[r * 65 + c];
  }
}

// ---------------- scores: 128x128 tile GEMM, 8x8 register blocking ----------
// No scalar-load operand path: both operands staged in LDS, read via
// ds_read_b128. Each thread: 8 items x 8 users, 64 FMA per k.
__global__ __launch_bounds__(256) void k_scores(const float* __restrict__ I,
                                                const float* __restrict__ Ut,
                                                const float* __restrict__ item_bias,
                                                float* __restrict__ out) {
  __shared__ float Is[64 * ST_P];   // [k][item], transposed, padded
  __shared__ float Us[64 * 128];    // [k][user]
  int tid = threadIdx.x;
  int i0 = blockIdx.x * 128;
  int ubase = blockIdx.y * 128;
  // stage I transposed: coalesced global float4 reads, LDS scatter (pad ST_P)
  {
    int c4 = tid & 15, r0 = tid >> 4;
#pragma unroll
    for (int s = 0; s < 8; s++) {
      int r = r0 + s * 16;
      int it = i0 + r;
      float4 v = make_float4(0.f, 0.f, 0.f, 0.f);
      if (it < N_ITEMS) v = *(const float4*)(I + (size_t)it * 64 + c4 * 4);
      Is[(c4 * 4 + 0) * ST_P + r] = v.x;
      Is[(c4 * 4 + 1) * ST_P + r] = v.y;
      Is[(c4 * 4 + 2) * ST_P + r] = v.z;
      Is[(c4 * 4 + 3) * ST_P + r] = v.w;
    }
  }
  // stage U: Us[k][u] = Ut[k*256 + ubase + u] (already k-major)
  {
    int u4 = tid & 31, k0 = tid >> 5;
#pragma unroll
    for (int s = 0; s < 8; s++) {
      int k = k0 + s * 8;
      float4 v = *(const float4*)(Ut + k * 256 + ubase + u4 * 4);
      *(float4*)(Us + k * 128 + u4 * 4) = v;
    }
  }
  __syncthreads();
  int tx = tid & 15;   // item group: items i0 + tx*8 .. +8
  int ty = tid >> 4;   // user group: users ubase + ty*8 .. +8
  float acc[8][8];
#pragma unroll
  for (int a = 0; a < 8; a++)
#pragma unroll
    for (int b = 0; b < 8; b++) acc[a][b] = 0.f;
  const float* ip = Is + tx * 8;
  const float* up = Us + ty * 8;
#pragma unroll 2
  for (int k = 0; k < 64; k++) {
    float4 iv0 = *(const float4*)(ip + k * ST_P);
    float4 iv1 = *(const float4*)(ip + k * ST_P + 4);
    float4 uv0 = *(const float4*)(up + k * 128);
    float4 uv1 = *(const float4*)(up + k * 128 + 4);
    float iv[8] = {iv0.x, iv0.y, iv0.z, iv0.w, iv1.x, iv1.y, iv1.z, iv1.w};
    float uv[8] = {uv0.x, uv0.y, uv0.z, uv0.w, uv1.x, uv1.y, uv1.z, uv1.w};
#pragma unroll
    for (int a = 0; a < 8; a++)
#pragma unroll
      for (int b = 0; b < 8; b++) acc[a][b] += iv[a] * uv[b];
  }
  // epilogue: add user bias (Ut[64*256+b]) + item bias, coalesced stores
  int ibase = i0 + tx * 8;
  float ib[8];
#pragma unroll
  for (int a = 0; a < 8; a++)
    ib[a] = (ibase + a < N_ITEMS) ? item_bias[ibase + a] : 0.f;
#pragma unroll
  for (int bb = 0; bb < 8; bb++) {
    int bu = ubase + ty * 8 + bb;
    float ubias = Ut[64 * 256 + bu];
    float* orow = out + (size_t)bu * N_ITEMS + ibase;
    if (ibase + 7 < N_ITEMS) {
      float4 s0 = make_float4(acc[0][bb] + ubias + ib[0], acc[1][bb] + ubias + ib[1],
                              acc[2][bb] + ubias + ib[2], acc[3][bb] + ubias + ib[3]);
      float4 s1 = make_float4(acc[4][bb] + ubias + ib[4], acc[5][bb] + ubias + ib[5],
                              acc[6][bb] + ubias + ib[6], acc[7][bb] + ubias + ib[7]);
      *(float4*)orow = s0;
      *(float4*)(orow + 4) = s1;
    } else {
#pragma unroll
      for (int a = 0; a < 8; a++)
        if (ibase + a < N_ITEMS) orow[a] = acc[a][bb] + ubias + ib[a];
    }
  }
}

extern "C" void kernel_launch(void* const* d_in, const int* in_sizes, int n_in,
                              void* d_out, int out_size, void* d_ws, size_t ws_size,
                              hipStream_t stream) {
  const float* user_emb  = (const float*)d_in[0];
  const float* item_emb  = (const float*)d_in[1];
  const float* user_bias = (const float*)d_in[2];
  const float* item_bias = (const float*)d_in[3];
  const float* pop_emb   = (const float*)d_in[4];
  const float* uW1 = (const float*)d_in[5];
  const float* ub1 = (const float*)d_in[6];
  const float* uW2 = (const float*)d_in[7];
  const float* ub2 = (const float*)d_in[8];
  const float* iW1 = (const float*)d_in[9];
  const float* ib1 = (const float*)d_in[10];
  const float* iW2 = (const float*)d_in[11];
  const float* ib2 = (const float*)d_in[12];
  const float* gW1 = (const float*)d_in[13];
  const float* gb1 = (const float*)d_in[14];
  const float* gW2 = (const float*)d_in[15];
  const float* gb2 = (const float*)d_in[16];
  const float* adj_vals = (const float*)d_in[17];
  const int* adj_rows = (const int*)d_in[18];
  const int* adj_cols = (const int*)d_in[19];
  const int* bins  = (const int*)d_in[20];
  const int* users = (const int*)d_in[21];
  float* out = (float*)d_out;

  // workspace layout (float offsets); total ~132.7 MB
  float* ws = (float*)d_ws;
  float* Oacc = ws;                    // 9,600,000
  float* bufA = ws + 9600000;          // 9,600,000
  float* bufB = ws + 19200000;         // 9,600,000 (gstage aliases this pre-SPMM)
  uint2* epack = (uint2*)(ws + 28800000);      // 2,000,000 * 8B
  int* rowptr = (int*)(ws + 32800000);         // 150,001
  int* cursor = (int*)(ws + 32960000);         // 150,000
  int* bsums  = (int*)(ws + 33120000);         // 1,024
  float* Ut   = ws + 33130000;                 // 65*256
  float* WT   = ws + 33150000;                 // 4,096 (uW1T)
  int* bcur   = (int*)(ws + 33170000);         // 147
  uint2* gstage = (uint2*)bufB;                // 2,000,000 * 8B, dead before SPMM L1
  const float* uW1T = WT;

  k_init<<<37500, 256, 0, stream>>>(user_emb, item_emb, bufA, Oacc, cursor);
  k_count<<<(NNZ + 255) / 256, 256, 0, stream>>>(adj_rows, cursor);
  k_scan1<<<NB_SCAN, 256, 0, stream>>>(cursor, rowptr, bsums, N_NODES);
  k_scan2<<<1, 1024, 0, stream>>>(bsums, NB_SCAN);
  k_scan3<<<NB_SCAN, 256, 0, stream>>>(rowptr, cursor, bsums, N_NODES);
  k_binit<<<1, 256, 0, stream>>>(rowptr, bcur);
  k_p1<<<P1_BLOCKS, 256, 0, stream>>>(adj_rows, adj_cols, adj_vals, bcur, gstage);
  k_p2<<<dim3(NBUCK, 2), 256, 0, stream>>>(rowptr, gstage, cursor, epack);

  k_spmm<<<37500, 256, 0, stream>>>(rowptr, epack, bufA, bufB, Oacc);
  k_spmm<<<37500, 256, 0, stream>>>(rowptr, epack, bufB, bufA, Oacc);
  k_spmm<<<37500, 256, 0, stream>>>(rowptr, epack, bufA, bufB, Oacc);

  k_wt<<<16, 256, 0, stream>>>(uW1, WT);
  k_user<<<4, 64, 0, stream>>>(Oacc, users, user_bias, uW1T, ub1, uW2, ub2, Ut);
  k_gate<<<782, 256, 0, stream>>>(Oacc, pop_emb, bins, gW1, gb1, gW2, gb2,
                                  iW1, ib1, iW2, ib2, bufA);
  k_scores<<<dim3(391, 2), 256, 0, stream>>>(bufA, Ut, item_bias, out);
}

// Round 5
// 806.121 us; speedup vs baseline: 1.1773x; 1.0356x over previous
//
#include <hip/hip_runtime.h>

#define N_USERS 100000
#define N_ITEMS 50000
#define N_NODES 150000
#define D 64
#define NNZ 2000000
#define BATCH 256
#define POP_BINS 10

#define NB_SCAN 586   // ceil(150000/256)

// bucketed scatter params
#define BSHIFT 10
#define NBUCK 147          // ceil(150000/1024)
#define P1_EPB 4096        // edges per block in pass 1
#define P1_BLOCKS 489      // ceil(NNZ/P1_EPB)

#define ST_P 130           // I-tile LDS pad for transposed stages

// ---------------- init: emb concat -> bufA, Oacc = 0.25*emb, zero counts ----
__global__ __launch_bounds__(256) void k_init(const float* __restrict__ ue,
                                              const float* __restrict__ ie,
                                              float* __restrict__ bufA,
                                              float* __restrict__ Oacc,
                                              int* __restrict__ counts) {
  int idx = blockIdx.x * 256 + threadIdx.x;
  if (idx < N_NODES * D) {
    float e = (idx < N_USERS * D) ? ue[idx] : ie[idx - N_USERS * D];
    bufA[idx] = e;
    Oacc[idx] = 0.25f * e;
  }
  if (idx < N_NODES) counts[idx] = 0;
}

// ---------------- CSR build ----------------
__global__ __launch_bounds__(256) void k_count(const int* __restrict__ rows,
                                               int* __restrict__ counts) {
  int e = blockIdx.x * 256 + threadIdx.x;
  if (e < NNZ) atomicAdd(&counts[rows[e]], 1);
}

__global__ __launch_bounds__(256) void k_scan1(const int* __restrict__ in,
                                               int* __restrict__ out,
                                               int* __restrict__ bsums, int n) {
  __shared__ int s[256];
  int t = threadIdx.x;
  int g = blockIdx.x * 256 + t;
  int v = (g < n) ? in[g] : 0;
  s[t] = v;
  __syncthreads();
  for (int off = 1; off < 256; off <<= 1) {
    int x = (t >= off) ? s[t - off] : 0;
    __syncthreads();
    s[t] += x;
    __syncthreads();
  }
  if (g < n) out[g] = s[t] - v;  // exclusive
  if (t == 255) bsums[blockIdx.x] = s[t];
}

__global__ __launch_bounds__(1024) void k_scan2(int* __restrict__ bs, int nb) {
  __shared__ int s[1024];
  int t = threadIdx.x;
  int v = (t < nb) ? bs[t] : 0;
  s[t] = v;
  __syncthreads();
  for (int off = 1; off < 1024; off <<= 1) {
    int x = (t >= off) ? s[t - off] : 0;
    __syncthreads();
    s[t] += x;
    __syncthreads();
  }
  if (t < nb) bs[t] = s[t] - v;  // exclusive
}

__global__ __launch_bounds__(256) void k_scan3(int* __restrict__ rowptr,
                                               int* __restrict__ cursor,
                                               const int* __restrict__ bsums, int n) {
  int g = blockIdx.x * 256 + threadIdx.x;
  if (g < n) {
    int v = rowptr[g] + bsums[blockIdx.x];
    rowptr[g] = v;
    cursor[g] = v;
  }
  if (g == 0) rowptr[n] = NNZ;
}

__global__ __launch_bounds__(256) void k_binit(const int* __restrict__ rowptr,
                                               int* __restrict__ bcur) {
  int t = threadIdx.x;
  if (t < NBUCK) bcur[t] = rowptr[t << BSHIFT];
}

// ---------------- pass 1: bucket edges, TWO-PASS (no per-thread arrays) -----
__global__ __launch_bounds__(256) void k_p1(const int* __restrict__ rows,
                                            const int* __restrict__ cols,
                                            const float* __restrict__ vals,
                                            int* __restrict__ bcur,
                                            uint2* __restrict__ gstage) {
  __shared__ int cnt[NBUCK];
  __shared__ int gbase[NBUCK];
  int t = threadIdx.x;
  if (t < NBUCK) cnt[t] = 0;
  __syncthreads();
  int base = blockIdx.x * P1_EPB;
  // pass A: count buckets
  for (int i = 0; i < 16; i++) {
    int e = base + i * 256 + t;
    if (e < NNZ) atomicAdd(&cnt[rows[e] >> BSHIFT], 1);
  }
  __syncthreads();
  if (t < NBUCK) {
    int c = cnt[t];
    gbase[t] = c ? atomicAdd(&bcur[t], c) : 0;
    cnt[t] = 0;
  }
  __syncthreads();
  // pass B: re-read (L2-hot) and scatter clustered
  for (int i = 0; i < 16; i++) {
    int e = base + i * 256 + t;
    if (e < NNZ) {
      int r = rows[e];
      int b = r >> BSHIFT;
      int rank = atomicAdd(&cnt[b], 1);
      unsigned key = ((unsigned)(r & 1023) << 18) | (unsigned)cols[e];
      gstage[gbase[b] + rank] = make_uint2(key, __float_as_uint(vals[e]));
    }
  }
}

// ---------------- pass 2: bucket-local scatter to CSR position --------------
__global__ __launch_bounds__(256) void k_p2(const int* __restrict__ rowptr,
                                            const uint2* __restrict__ gstage,
                                            int* __restrict__ cursor,
                                            uint2* __restrict__ epack) {
  int b = blockIdx.x;
  int s = rowptr[b << BSHIFT];
  int rend = (b + 1) << BSHIFT;
  if (rend > N_NODES) rend = N_NODES;
  int e = rowptr[rend];
  int half = (e - s) >> 1;
  int lo = blockIdx.y ? (s + half) : s;
  int hi = blockIdx.y ? e : (s + half);
  int rowbase = b << BSHIFT;
  for (int j = lo + threadIdx.x; j < hi; j += 256) {
    uint2 ed = gstage[j];
    int row = rowbase + (int)(ed.x >> 18);
    int col = (int)(ed.x & 0x3FFFFu);
    int pos = atomicAdd(&cursor[row], 1);
    epack[pos] = make_uint2((unsigned)col, ed.y);
  }
}

// ---------------- SPMM: one wave per row, scalar edge loads ----------------
__global__ __launch_bounds__(256) void k_spmm(const int* __restrict__ rowptr,
                                              const uint2* __restrict__ epack,
                                              const float* __restrict__ Ein,
                                              float* __restrict__ Eout,
                                              float* __restrict__ Oacc) {
  int wave = blockIdx.x * 4 + (threadIdx.x >> 6);
  int row = __builtin_amdgcn_readfirstlane(wave);  // force uniform -> s_loads
  if (row >= N_NODES) return;
  int lane = threadIdx.x & 63;
  int beg = rowptr[row];
  int end = rowptr[row + 1];
  float acc0 = 0.f, acc1 = 0.f;
  int j = beg;
  for (; j + 3 < end; j += 4) {
    uint2 e0 = epack[j], e1 = epack[j + 1], e2 = epack[j + 2], e3 = epack[j + 3];
    acc0 += __uint_as_float(e0.y) * Ein[(int)e0.x * D + lane];
    acc1 += __uint_as_float(e1.y) * Ein[(int)e1.x * D + lane];
    acc0 += __uint_as_float(e2.y) * Ein[(int)e2.x * D + lane];
    acc1 += __uint_as_float(e3.y) * Ein[(int)e3.x * D + lane];
  }
  for (; j < end; ++j) {
    uint2 e0 = epack[j];
    acc0 += __uint_as_float(e0.y) * Ein[(int)e0.x * D + lane];
  }
  float acc = acc0 + acc1;
  int o = row * D + lane;
  Eout[o] = acc;
  Oacc[o] += 0.25f * acc;
}

// ---------------- weight transpose: uW1T[64][64] (for k_user) ---------------
__global__ __launch_bounds__(256) void k_wt(const float* __restrict__ uW1,
                                            float* __restrict__ WT) {
  int t = blockIdx.x * 256 + threadIdx.x;
  if (t < 4096) {
    int o = t >> 6, k = t & 63;
    WT[t] = uW1[k * 64 + o];
  }
}

// ---------------- pop-row precompute: hp[b]=p_b@gW1_p, pp1[b]=p_b@iW1 -------
__global__ __launch_bounds__(256) void k_pw(const float* __restrict__ pop,
                                            const float* __restrict__ gW1,
                                            const float* __restrict__ iW1,
                                            float* __restrict__ hp,
                                            float* __restrict__ pp1) {
  for (int idx = threadIdx.x; idx < 2 * POP_BINS * 64; idx += 256) {
    int q = idx;
    bool second = q >= POP_BINS * 64;
    if (second) q -= POP_BINS * 64;
    int b = q >> 6, o = q & 63;
    float s = 0.f;
    if (!second) {
      for (int k = 0; k < 64; k++) s += pop[b * 64 + k] * gW1[(64 + k) * 64 + o];
      hp[q] = s;
    } else {
      for (int k = 0; k < 64; k++) s += pop[b * 64 + k] * iW1[k * 64 + o];
      pp1[q] = s;
    }
  }
}

// ---------------- user MLP: thread per user, scalar weights, write U^T ------
__global__ __launch_bounds__(64) void k_user(const float* __restrict__ Oacc,
                                             const int* __restrict__ users,
                                             const float* __restrict__ ubias,
                                             const float* __restrict__ uW1T,
                                             const float* __restrict__ ub1,
                                             const float* __restrict__ uW2,
                                             const float* __restrict__ ub2,
                                             float* __restrict__ Ut) {
  int b = blockIdx.x * 64 + threadIdx.x;
  int u = users[b];
  float x[64];
  const float4* xr = (const float4*)(Oacc + (size_t)u * 64);
#pragma unroll
  for (int q = 0; q < 16; q++) {
    float4 t4 = xr[q];
    x[4 * q] = t4.x; x[4 * q + 1] = t4.y; x[4 * q + 2] = t4.z; x[4 * q + 3] = t4.w;
  }
  float acc[64];
#pragma unroll
  for (int o2 = 0; o2 < 64; o2++) acc[o2] = ub2[o2];
#pragma unroll 1
  for (int o = 0; o < 64; o++) {
    const float* w = uW1T + o * 64;
    float a0 = ub1[o], a1 = 0.f, a2 = 0.f, a3 = 0.f;
#pragma unroll
    for (int k = 0; k < 64; k += 4) {
      a0 += x[k] * w[k]; a1 += x[k + 1] * w[k + 1];
      a2 += x[k + 2] * w[k + 2]; a3 += x[k + 3] * w[k + 3];
    }
    float hv = a0 + a1 + a2 + a3;
    hv = hv > 0.f ? hv : 0.f;
    const float* w2 = uW2 + o * 64;
#pragma unroll
    for (int o2 = 0; o2 < 64; o2++) acc[o2] += hv * w2[o2];
  }
#pragma unroll 1
  for (int o2 = 0; o2 < 64; o2++) Ut[o2 * 256 + b] = acc[o2];
  Ut[64 * 256 + b] = ubias[u];  // BIAS_SCALE = 1.0
}

// ---------------- GEMM1: [G|T] = X @ [gW1_x | iW1]  (128x128 tile, K=64) ----
__global__ __launch_bounds__(256) void k_gemm1(const float* __restrict__ Oacc,
                                               const float* __restrict__ gW1,
                                               const float* __restrict__ iW1,
                                               float* __restrict__ G,
                                               float* __restrict__ T) {
  __shared__ float Is[64 * ST_P];   // [k][item]
  __shared__ float Bs[64 * 128];    // [k][o]  o<64 -> gW1_x, o>=64 -> iW1
  int tid = threadIdx.x;
  int i0 = blockIdx.x * 128;
  {
    int c4 = tid & 15, r0 = tid >> 4;
#pragma unroll
    for (int s = 0; s < 8; s++) {
      int r = r0 + s * 16;
      int it = i0 + r;
      float4 v = make_float4(0.f, 0.f, 0.f, 0.f);
      if (it < N_ITEMS) v = *(const float4*)(Oacc + (size_t)(N_USERS + it) * 64 + c4 * 4);
      Is[(c4 * 4 + 0) * ST_P + r] = v.x;
      Is[(c4 * 4 + 1) * ST_P + r] = v.y;
      Is[(c4 * 4 + 2) * ST_P + r] = v.z;
      Is[(c4 * 4 + 3) * ST_P + r] = v.w;
    }
  }
  for (int idx = tid; idx < 64 * 128; idx += 256) {
    int k = idx >> 7, o = idx & 127;
    Bs[idx] = (o < 64) ? gW1[k * 64 + o] : iW1[k * 64 + (o - 64)];
  }
  __syncthreads();
  int tx = tid & 15, ty = tid >> 4;
  float acc[8][8];
#pragma unroll
  for (int a = 0; a < 8; a++)
#pragma unroll
    for (int b = 0; b < 8; b++) acc[a][b] = 0.f;
  const float* ip = Is + tx * 8;
  const float* wp = Bs + ty * 8;
#pragma unroll 2
  for (int k = 0; k < 64; k++) {
    float4 iv0 = *(const float4*)(ip + k * ST_P);
    float4 iv1 = *(const float4*)(ip + k * ST_P + 4);
    float4 wv0 = *(const float4*)(wp + k * 128);
    float4 wv1 = *(const float4*)(wp + k * 128 + 4);
    float iv[8] = {iv0.x, iv0.y, iv0.z, iv0.w, iv1.x, iv1.y, iv1.z, iv1.w};
    float wv[8] = {wv0.x, wv0.y, wv0.z, wv0.w, wv1.x, wv1.y, wv1.z, wv1.w};
#pragma unroll
    for (int a = 0; a < 8; a++)
#pragma unroll
      for (int b = 0; b < 8; b++) acc[a][b] += iv[a] * wv[b];
  }
  int ibase = i0 + tx * 8;
  int o0 = ty * 8;
  float* dst = (o0 < 64) ? G : T;
  int oc = o0 & 63;
#pragma unroll
  for (int a = 0; a < 8; a++) {
    int it = ibase + a;
    if (it < N_ITEMS) {
      float4 s0 = make_float4(acc[a][0], acc[a][1], acc[a][2], acc[a][3]);
      float4 s1 = make_float4(acc[a][4], acc[a][5], acc[a][6], acc[a][7]);
      *(float4*)(dst + (size_t)it * 64 + oc) = s0;
      *(float4*)(dst + (size_t)it * 64 + oc + 4) = s1;
    }
  }
}

// ---------------- z + fuse: one wave per item --------------------------------
__global__ __launch_bounds__(256) void k_zf(const float* __restrict__ G,
                                            const float* __restrict__ T,
                                            const int* __restrict__ bins,
                                            const float* __restrict__ hp,
                                            const float* __restrict__ pp1,
                                            const float* __restrict__ gb1,
                                            const float* __restrict__ gW2,
                                            const float* __restrict__ gb2,
                                            const float* __restrict__ ib1,
                                            float* __restrict__ H1) {
  int item = blockIdx.x * 4 + (threadIdx.x >> 6);
  if (item >= N_ITEMS) return;
  int lane = threadIdx.x & 63;
  int bin = bins[item];
  float g = G[(size_t)item * 64 + lane];
  float t = T[(size_t)item * 64 + lane];
  float v = g + hp[bin * 64 + lane] + gb1[lane];
  v = (v > 0.f ? v : 0.f) * gW2[lane];
#pragma unroll
  for (int off = 32; off > 0; off >>= 1) v += __shfl_xor(v, off, 64);
  float z = 1.f / (1.f + expf(-(v + gb2[0])));
  float h = (1.f - z) * t + z * pp1[bin * 64 + lane] + ib1[lane];
  H1[(size_t)item * 64 + lane] = h > 0.f ? h : 0.f;
}

// ---------------- GEMM2: I = H1 @ iW2 + ib2  (128x64 tile, K=64) ------------
__global__ __launch_bounds__(256) void k_gemm2(const float* __restrict__ H1,
                                               const float* __restrict__ iW2,
                                               const float* __restrict__ ib2,
                                               float* __restrict__ I) {
  __shared__ float Is[64 * ST_P];   // [k][item]
  __shared__ float Bs[64 * 64];     // [k][o]
  int tid = threadIdx.x;
  int i0 = blockIdx.x * 128;
  {
    int c4 = tid & 15, r0 = tid >> 4;
#pragma unroll
    for (int s = 0; s < 8; s++) {
      int r = r0 + s * 16;
      int it = i0 + r;
      float4 v = make_float4(0.f, 0.f, 0.f, 0.f);
      if (it < N_ITEMS) v = *(const float4*)(H1 + (size_t)it * 64 + c4 * 4);
      Is[(c4 * 4 + 0) * ST_P + r] = v.x;
      Is[(c4 * 4 + 1) * ST_P + r] = v.y;
      Is[(c4 * 4 + 2) * ST_P + r] = v.z;
      Is[(c4 * 4 + 3) * ST_P + r] = v.w;
    }
  }
  for (int idx = tid; idx < 64 * 64; idx += 256) Bs[idx] = iW2[idx];
  __syncthreads();
  int tx = tid & 15, ty = tid >> 4;   // 8 items x 4 outs
  float acc[8][4];
#pragma unroll
  for (int a = 0; a < 8; a++)
#pragma unroll
    for (int b = 0; b < 4; b++) acc[a][b] = 0.f;
  const float* ip = Is + tx * 8;
  const float* wp = Bs + ty * 4;
#pragma unroll 2
  for (int k = 0; k < 64; k++) {
    float4 iv0 = *(const float4*)(ip + k * ST_P);
    float4 iv1 = *(const float4*)(ip + k * ST_P + 4);
    float4 wv = *(const float4*)(wp + k * 64);
    float iv[8] = {iv0.x, iv0.y, iv0.z, iv0.w, iv1.x, iv1.y, iv1.z, iv1.w};
    float wvv[4] = {wv.x, wv.y, wv.z, wv.w};
#pragma unroll
    for (int a = 0; a < 8; a++)
#pragma unroll
      for (int b = 0; b < 4; b++) acc[a][b] += iv[a] * wvv[b];
  }
  int ibase = i0 + tx * 8;
  int oc = ty * 4;
  float b0 = ib2[oc], b1 = ib2[oc + 1], b2 = ib2[oc + 2], b3 = ib2[oc + 3];
#pragma unroll
  for (int a = 0; a < 8; a++) {
    int it = ibase + a;
    if (it < N_ITEMS) {
      float4 s0 = make_float4(acc[a][0] + b0, acc[a][1] + b1,
                              acc[a][2] + b2, acc[a][3] + b3);
      *(float4*)(I + (size_t)it * 64 + oc) = s0;
    }
  }
}

// ---------------- scores: 128x128 tile GEMM, 8x8 register blocking ----------
__global__ __launch_bounds__(256) void k_scores(const float* __restrict__ I,
                                                const float* __restrict__ Ut,
                                                const float* __restrict__ item_bias,
                                                float* __restrict__ out) {
  __shared__ float Is[64 * ST_P];   // [k][item], transposed, padded
  __shared__ float Us[64 * 128];    // [k][user]
  int tid = threadIdx.x;
  int i0 = blockIdx.x * 128;
  int ubase = blockIdx.y * 128;
  {
    int c4 = tid & 15, r0 = tid >> 4;
#pragma unroll
    for (int s = 0; s < 8; s++) {
      int r = r0 + s * 16;
      int it = i0 + r;
      float4 v = make_float4(0.f, 0.f, 0.f, 0.f);
      if (it < N_ITEMS) v = *(const float4*)(I + (size_t)it * 64 + c4 * 4);
      Is[(c4 * 4 + 0) * ST_P + r] = v.x;
      Is[(c4 * 4 + 1) * ST_P + r] = v.y;
      Is[(c4 * 4 + 2) * ST_P + r] = v.z;
      Is[(c4 * 4 + 3) * ST_P + r] = v.w;
    }
  }
  {
    int u4 = tid & 31, k0 = tid >> 5;
#pragma unroll
    for (int s = 0; s < 8; s++) {
      int k = k0 + s * 8;
      float4 v = *(const float4*)(Ut + k * 256 + ubase + u4 * 4);
      *(float4*)(Us + k * 128 + u4 * 4) = v;
    }
  }
  __syncthreads();
  int tx = tid & 15;
  int ty = tid >> 4;
  float acc[8][8];
#pragma unroll
  for (int a = 0; a < 8; a++)
#pragma unroll
    for (int b = 0; b < 8; b++) acc[a][b] = 0.f;
  const float* ip = Is + tx * 8;
  const float* up = Us + ty * 8;
#pragma unroll 2
  for (int k = 0; k < 64; k++) {
    float4 iv0 = *(const float4*)(ip + k * ST_P);
    float4 iv1 = *(const float4*)(ip + k * ST_P + 4);
    float4 uv0 = *(const float4*)(up + k * 128);
    float4 uv1 = *(const float4*)(up + k * 128 + 4);
    float iv[8] = {iv0.x, iv0.y, iv0.z, iv0.w, iv1.x, iv1.y, iv1.z, iv1.w};
    float uv[8] = {uv0.x, uv0.y, uv0.z, uv0.w, uv1.x, uv1.y, uv1.z, uv1.w};
#pragma unroll
    for (int a = 0; a < 8; a++)
#pragma unroll
      for (int b = 0; b < 8; b++) acc[a][b] += iv[a] * uv[b];
  }
  int ibase = i0 + tx * 8;
  float ib[8];
#pragma unroll
  for (int a = 0; a < 8; a++)
    ib[a] = (ibase + a < N_ITEMS) ? item_bias[ibase + a] : 0.f;
#pragma unroll
  for (int bb = 0; bb < 8; bb++) {
    int bu = ubase + ty * 8 + bb;
    float ubias = Ut[64 * 256 + bu];
    float* orow = out + (size_t)bu * N_ITEMS + ibase;
    if (ibase + 7 < N_ITEMS) {
      float4 s0 = make_float4(acc[0][bb] + ubias + ib[0], acc[1][bb] + ubias + ib[1],
                              acc[2][bb] + ubias + ib[2], acc[3][bb] + ubias + ib[3]);
      float4 s1 = make_float4(acc[4][bb] + ubias + ib[4], acc[5][bb] + ubias + ib[5],
                              acc[6][bb] + ubias + ib[6], acc[7][bb] + ubias + ib[7]);
      *(float4*)orow = s0;
      *(float4*)(orow + 4) = s1;
    } else {
#pragma unroll
      for (int a = 0; a < 8; a++)
        if (ibase + a < N_ITEMS) orow[a] = acc[a][bb] + ubias + ib[a];
    }
  }
}

extern "C" void kernel_launch(void* const* d_in, const int* in_sizes, int n_in,
                              void* d_out, int out_size, void* d_ws, size_t ws_size,
                              hipStream_t stream) {
  const float* user_emb  = (const float*)d_in[0];
  const float* item_emb  = (const float*)d_in[1];
  const float* user_bias = (const float*)d_in[2];
  const float* item_bias = (const float*)d_in[3];
  const float* pop_emb   = (const float*)d_in[4];
  const float* uW1 = (const float*)d_in[5];
  const float* ub1 = (const float*)d_in[6];
  const float* uW2 = (const float*)d_in[7];
  const float* ub2 = (const float*)d_in[8];
  const float* iW1 = (const float*)d_in[9];
  const float* ib1 = (const float*)d_in[10];
  const float* iW2 = (const float*)d_in[11];
  const float* ib2 = (const float*)d_in[12];
  const float* gW1 = (const float*)d_in[13];
  const float* gb1 = (const float*)d_in[14];
  const float* gW2 = (const float*)d_in[15];
  const float* gb2 = (const float*)d_in[16];
  const float* adj_vals = (const float*)d_in[17];
  const int* adj_rows = (const int*)d_in[18];
  const int* adj_cols = (const int*)d_in[19];
  const int* bins  = (const int*)d_in[20];
  const int* users = (const int*)d_in[21];
  float* out = (float*)d_out;

  // workspace layout (float offsets); total ~132.7 MB
  float* ws = (float*)d_ws;
  float* Oacc = ws;                    // 9,600,000
  float* bufA = ws + 9600000;          // 9,600,000 (G/T/H1 after spmm)
  float* bufB = ws + 19200000;         // 9,600,000 (gstage pre-spmm; I after)
  uint2* epack = (uint2*)(ws + 28800000);      // 2,000,000 * 8B
  int* rowptr = (int*)(ws + 32800000);         // 150,001
  int* cursor = (int*)(ws + 32960000);         // 150,000
  int* bsums  = (int*)(ws + 33120000);         // 1,024
  float* Ut   = ws + 33130000;                 // 65*256
  float* WT   = ws + 33150000;                 // 4,096 (uW1T)
  float* hp   = ws + 33160000;                 // 640
  float* pp1  = ws + 33161000;                 // 640
  int* bcur   = (int*)(ws + 33170000);         // 147
  uint2* gstage = (uint2*)bufB;
  float* G  = bufA;                            // 3,200,000
  float* Tm = bufA + 3200000;                  // 3,200,000
  float* H1 = bufA + 6400000;                  // 3,200,000
  float* I  = bufB;                            // 3,200,000
  const float* uW1T = WT;

  k_init<<<37500, 256, 0, stream>>>(user_emb, item_emb, bufA, Oacc, cursor);
  k_count<<<(NNZ + 255) / 256, 256, 0, stream>>>(adj_rows, cursor);
  k_scan1<<<NB_SCAN, 256, 0, stream>>>(cursor, rowptr, bsums, N_NODES);
  k_scan2<<<1, 1024, 0, stream>>>(bsums, NB_SCAN);
  k_scan3<<<NB_SCAN, 256, 0, stream>>>(rowptr, cursor, bsums, N_NODES);
  k_binit<<<1, 256, 0, stream>>>(rowptr, bcur);
  k_p1<<<P1_BLOCKS, 256, 0, stream>>>(adj_rows, adj_cols, adj_vals, bcur, gstage);
  k_p2<<<dim3(NBUCK, 2), 256, 0, stream>>>(rowptr, gstage, cursor, epack);

  k_spmm<<<37500, 256, 0, stream>>>(rowptr, epack, bufA, bufB, Oacc);
  k_spmm<<<37500, 256, 0, stream>>>(rowptr, epack, bufB, bufA, Oacc);
  k_spmm<<<37500, 256, 0, stream>>>(rowptr, epack, bufA, bufB, Oacc);

  k_wt<<<16, 256, 0, stream>>>(uW1, WT);
  k_pw<<<1, 256, 0, stream>>>(pop_emb, gW1, iW1, hp, pp1);
  k_user<<<4, 64, 0, stream>>>(Oacc, users, user_bias, uW1T, ub1, uW2, ub2, Ut);
  k_gemm1<<<391, 256, 0, stream>>>(Oacc, gW1, iW1, G, Tm);
  k_zf<<<12500, 256, 0, stream>>>(G, Tm, bins, hp, pp1, gb1, gW2, gb2, ib1, H1);
  k_gemm2<<<391, 256, 0, stream>>>(H1, iW2, ib2, I);
  k_scores<<<dim3(391, 2), 256, 0, stream>>>(I, Ut, item_bias, out);
}

// Round 6
// 668.480 us; speedup vs baseline: 1.4197x; 1.2059x over previous
//
#include <hip/hip_runtime.h>

#define N_USERS 100000
#define N_ITEMS 50000
#define N_NODES 150000
#define D 64
#define NNZ 2000000
#define BATCH 256
#define POP_BINS 10

// bucketed CSR params
#define BSH 9
#define NB2 293            // ceil(150000/512)
#define CAP 8192           // max edges per bucket (mean 6827, sigma ~82)
#define P1_EPB 4096        // edges per block in pass 1
#define P1_BLOCKS 489      // ceil(NNZ/P1_EPB)

#define ST_P 130           // I-tile LDS pad for transposed stages

// ---------------- bucket count: LDS histogram -> global ----------------------
__global__ __launch_bounds__(256) void k_bcount(const int* __restrict__ rows,
                                                int* __restrict__ bcnt) {
  __shared__ int c[NB2];
  int t = threadIdx.x;
  for (int i = t; i < NB2; i += 256) c[i] = 0;
  __syncthreads();
  int base = blockIdx.x * P1_EPB;
  for (int i = 0; i < 16; i++) {
    int e = base + i * 256 + t;
    if (e < NNZ) atomicAdd(&c[rows[e] >> BSH], 1);
  }
  __syncthreads();
  for (int i = t; i < NB2; i += 256)
    if (c[i]) atomicAdd(&bcnt[i], c[i]);
}

// ---------------- bucket scan: exclusive, in-place (becomes bcur) ------------
__global__ __launch_bounds__(512) void k_bscan(int* __restrict__ bcnt) {
  __shared__ int s[512];
  int t = threadIdx.x;
  int v = (t < NB2) ? bcnt[t] : 0;
  s[t] = v;
  __syncthreads();
  for (int o = 1; o < 512; o <<= 1) {
    int x = (t >= o) ? s[t - o] : 0;
    __syncthreads();
    s[t] += x;
    __syncthreads();
  }
  if (t < NB2) bcnt[t] = s[t] - v;  // exclusive base; p1 advances to inclusive
}

// ---------------- pass 1: bucket edges, TWO-PASS (no per-thread arrays) -----
__global__ __launch_bounds__(256) void k_p1(const int* __restrict__ rows,
                                            const int* __restrict__ cols,
                                            const float* __restrict__ vals,
                                            int* __restrict__ bcur,
                                            uint2* __restrict__ gstage) {
  __shared__ int cnt[NB2];
  __shared__ int gbase[NB2];
  int t = threadIdx.x;
  for (int i = t; i < NB2; i += 256) cnt[i] = 0;
  __syncthreads();
  int base = blockIdx.x * P1_EPB;
  // pass A: count buckets
  for (int i = 0; i < 16; i++) {
    int e = base + i * 256 + t;
    if (e < NNZ) atomicAdd(&cnt[rows[e] >> BSH], 1);
  }
  __syncthreads();
  for (int i = t; i < NB2; i += 256) {
    int c = cnt[i];
    gbase[i] = c ? atomicAdd(&bcur[i], c) : 0;
    cnt[i] = 0;
  }
  __syncthreads();
  // pass B: re-read (L2-hot) and scatter clustered
  for (int i = 0; i < 16; i++) {
    int e = base + i * 256 + t;
    if (e < NNZ) {
      int r = rows[e];
      int b = r >> BSH;
      int rank = atomicAdd(&cnt[b], 1);
      unsigned key = ((unsigned)(r & 511) << 18) | (unsigned)cols[e];
      gstage[gbase[b] + rank] = make_uint2(key, __float_as_uint(vals[e]));
    }
  }
}

// ---------------- pass 2: per-bucket LDS counting sort, contiguous writes ---
// Also produces rowptr (bucketbase + local exclusive scan).
__global__ __launch_bounds__(256) void k_p2(const int* __restrict__ bcur,
                                            const uint2* __restrict__ gstage,
                                            uint2* __restrict__ epack,
                                            int* __restrict__ rowptr) {
  __shared__ int cnt[512];
  __shared__ int off[512];
  __shared__ int s[256];
  __shared__ uint2 buf[CAP];
  int b = blockIdx.x, t = threadIdx.x;
  int base = (b == 0) ? 0 : bcur[b - 1];  // post-p1 bcur = inclusive scan
  int end = bcur[b];
  int n = end - base;
  cnt[t] = 0;
  cnt[t + 256] = 0;
  __syncthreads();
  for (int j = t; j < n; j += 256)
    atomicAdd(&cnt[gstage[base + j].x >> 18], 1);
  __syncthreads();
  // scan 512 entries (each thread owns 2)
  int c0 = cnt[2 * t], c1 = cnt[2 * t + 1];
  s[t] = c0 + c1;
  __syncthreads();
  for (int o = 1; o < 256; o <<= 1) {
    int x = (t >= o) ? s[t - o] : 0;
    __syncthreads();
    s[t] += x;
    __syncthreads();
  }
  int ex = t ? s[t - 1] : 0;
  off[2 * t] = ex;
  off[2 * t + 1] = ex + c0;
  int gr = (b << BSH) + 2 * t;
  if (gr < N_NODES) rowptr[gr] = base + ex;
  if (gr + 1 < N_NODES) rowptr[gr + 1] = base + ex + c0;
  if (b == NB2 - 1 && t == 0) rowptr[N_NODES] = NNZ;
  __syncthreads();
  for (int j = t; j < n; j += 256) {
    uint2 ed = gstage[base + j];
    int lr = ed.x >> 18;
    int pos = atomicAdd(&off[lr], 1);
    buf[pos] = make_uint2(ed.x & 0x3FFFFu, ed.y);
  }
  __syncthreads();
  for (int j = t; j < n; j += 256) epack[base + j] = buf[j];
}

// ---------------- SPMM layer 1: gather from emb directly, init Oacc ---------
__global__ __launch_bounds__(256) void k_spmm1(const int* __restrict__ rowptr,
                                               const uint2* __restrict__ epack,
                                               const float* __restrict__ ue,
                                               const float* __restrict__ ie,
                                               float* __restrict__ Eout,
                                               float* __restrict__ Oacc) {
  int wave = blockIdx.x * 4 + (threadIdx.x >> 6);
  int row = __builtin_amdgcn_readfirstlane(wave);
  if (row >= N_NODES) return;
  int lane = threadIdx.x & 63;
  int beg = rowptr[row];
  int end = rowptr[row + 1];
  float acc0 = 0.f, acc1 = 0.f;
  int j = beg;
  for (; j + 3 < end; j += 4) {
    uint2 e0 = epack[j], e1 = epack[j + 1], e2 = epack[j + 2], e3 = epack[j + 3];
    int c0 = (int)e0.x, c1 = (int)e1.x, c2 = (int)e2.x, c3 = (int)e3.x;
    const float* s0 = (c0 < N_USERS) ? ue + (size_t)c0 * D : ie + (size_t)(c0 - N_USERS) * D;
    const float* s1 = (c1 < N_USERS) ? ue + (size_t)c1 * D : ie + (size_t)(c1 - N_USERS) * D;
    const float* s2 = (c2 < N_USERS) ? ue + (size_t)c2 * D : ie + (size_t)(c2 - N_USERS) * D;
    const float* s3 = (c3 < N_USERS) ? ue + (size_t)c3 * D : ie + (size_t)(c3 - N_USERS) * D;
    acc0 += __uint_as_float(e0.y) * s0[lane];
    acc1 += __uint_as_float(e1.y) * s1[lane];
    acc0 += __uint_as_float(e2.y) * s2[lane];
    acc1 += __uint_as_float(e3.y) * s3[lane];
  }
  for (; j < end; ++j) {
    uint2 e0 = epack[j];
    int c0 = (int)e0.x;
    const float* s0 = (c0 < N_USERS) ? ue + (size_t)c0 * D : ie + (size_t)(c0 - N_USERS) * D;
    acc0 += __uint_as_float(e0.y) * s0[lane];
  }
  float acc = acc0 + acc1;
  float e = (row < N_USERS) ? ue[(size_t)row * D + lane]
                            : ie[(size_t)(row - N_USERS) * D + lane];
  int o = row * D + lane;
  Eout[o] = acc;
  Oacc[o] = 0.25f * (e + acc);
}

// ---------------- SPMM layers 2,3 -------------------------------------------
__global__ __launch_bounds__(256) void k_spmm(const int* __restrict__ rowptr,
                                              const uint2* __restrict__ epack,
                                              const float* __restrict__ Ein,
                                              float* __restrict__ Eout,
                                              float* __restrict__ Oacc) {
  int wave = blockIdx.x * 4 + (threadIdx.x >> 6);
  int row = __builtin_amdgcn_readfirstlane(wave);
  if (row >= N_NODES) return;
  int lane = threadIdx.x & 63;
  int beg = rowptr[row];
  int end = rowptr[row + 1];
  float acc0 = 0.f, acc1 = 0.f;
  int j = beg;
  for (; j + 3 < end; j += 4) {
    uint2 e0 = epack[j], e1 = epack[j + 1], e2 = epack[j + 2], e3 = epack[j + 3];
    acc0 += __uint_as_float(e0.y) * Ein[(int)e0.x * D + lane];
    acc1 += __uint_as_float(e1.y) * Ein[(int)e1.x * D + lane];
    acc0 += __uint_as_float(e2.y) * Ein[(int)e2.x * D + lane];
    acc1 += __uint_as_float(e3.y) * Ein[(int)e3.x * D + lane];
  }
  for (; j < end; ++j) {
    uint2 e0 = epack[j];
    acc0 += __uint_as_float(e0.y) * Ein[(int)e0.x * D + lane];
  }
  float acc = acc0 + acc1;
  int o = row * D + lane;
  Eout[o] = acc;
  Oacc[o] += 0.25f * acc;
}

// ---------------- weight transpose: uW1T[64][64] (for k_user) ---------------
__global__ __launch_bounds__(256) void k_wt(const float* __restrict__ uW1,
                                            float* __restrict__ WT) {
  int t = blockIdx.x * 256 + threadIdx.x;
  if (t < 4096) {
    int o = t >> 6, k = t & 63;
    WT[t] = uW1[k * 64 + o];
  }
}

// ---------------- pop-row precompute: hp[b]=p_b@gW1_p, pp1[b]=p_b@iW1 -------
__global__ __launch_bounds__(256) void k_pw(const float* __restrict__ pop,
                                            const float* __restrict__ gW1,
                                            const float* __restrict__ iW1,
                                            float* __restrict__ hp,
                                            float* __restrict__ pp1) {
  for (int idx = threadIdx.x; idx < 2 * POP_BINS * 64; idx += 256) {
    int q = idx;
    bool second = q >= POP_BINS * 64;
    if (second) q -= POP_BINS * 64;
    int b = q >> 6, o = q & 63;
    float s = 0.f;
    if (!second) {
      for (int k = 0; k < 64; k++) s += pop[b * 64 + k] * gW1[(64 + k) * 64 + o];
      hp[q] = s;
    } else {
      for (int k = 0; k < 64; k++) s += pop[b * 64 + k] * iW1[k * 64 + o];
      pp1[q] = s;
    }
  }
}

// ---------------- user MLP: thread per user, scalar weights, write U^T ------
__global__ __launch_bounds__(64) void k_user(const float* __restrict__ Oacc,
                                             const int* __restrict__ users,
                                             const float* __restrict__ ubias,
                                             const float* __restrict__ uW1T,
                                             const float* __restrict__ ub1,
                                             const float* __restrict__ uW2,
                                             const float* __restrict__ ub2,
                                             float* __restrict__ Ut) {
  int b = blockIdx.x * 64 + threadIdx.x;
  int u = users[b];
  float x[64];
  const float4* xr = (const float4*)(Oacc + (size_t)u * 64);
#pragma unroll
  for (int q = 0; q < 16; q++) {
    float4 t4 = xr[q];
    x[4 * q] = t4.x; x[4 * q + 1] = t4.y; x[4 * q + 2] = t4.z; x[4 * q + 3] = t4.w;
  }
  float acc[64];
#pragma unroll
  for (int o2 = 0; o2 < 64; o2++) acc[o2] = ub2[o2];
#pragma unroll 1
  for (int o = 0; o < 64; o++) {
    const float* w = uW1T + o * 64;
    float a0 = ub1[o], a1 = 0.f, a2 = 0.f, a3 = 0.f;
#pragma unroll
    for (int k = 0; k < 64; k += 4) {
      a0 += x[k] * w[k]; a1 += x[k + 1] * w[k + 1];
      a2 += x[k + 2] * w[k + 2]; a3 += x[k + 3] * w[k + 3];
    }
    float hv = a0 + a1 + a2 + a3;
    hv = hv > 0.f ? hv : 0.f;
    const float* w2 = uW2 + o * 64;
#pragma unroll
    for (int o2 = 0; o2 < 64; o2++) acc[o2] += hv * w2[o2];
  }
#pragma unroll 1
  for (int o2 = 0; o2 < 64; o2++) Ut[o2 * 256 + b] = acc[o2];
  Ut[64 * 256 + b] = ubias[u];  // BIAS_SCALE = 1.0
}

// ---------------- GEMM1: [G|T] = X @ [gW1_x | iW1]  (128x128 tile, K=64) ----
__global__ __launch_bounds__(256) void k_gemm1(const float* __restrict__ Oacc,
                                               const float* __restrict__ gW1,
                                               const float* __restrict__ iW1,
                                               float* __restrict__ G,
                                               float* __restrict__ T) {
  __shared__ float Is[64 * ST_P];
  __shared__ float Bs[64 * 128];
  int tid = threadIdx.x;
  int i0 = blockIdx.x * 128;
  {
    int c4 = tid & 15, r0 = tid >> 4;
#pragma unroll
    for (int s = 0; s < 8; s++) {
      int r = r0 + s * 16;
      int it = i0 + r;
      float4 v = make_float4(0.f, 0.f, 0.f, 0.f);
      if (it < N_ITEMS) v = *(const float4*)(Oacc + (size_t)(N_USERS + it) * 64 + c4 * 4);
      Is[(c4 * 4 + 0) * ST_P + r] = v.x;
      Is[(c4 * 4 + 1) * ST_P + r] = v.y;
      Is[(c4 * 4 + 2) * ST_P + r] = v.z;
      Is[(c4 * 4 + 3) * ST_P + r] = v.w;
    }
  }
  for (int idx = tid; idx < 64 * 128; idx += 256) {
    int k = idx >> 7, o = idx & 127;
    Bs[idx] = (o < 64) ? gW1[k * 64 + o] : iW1[k * 64 + (o - 64)];
  }
  __syncthreads();
  int tx = tid & 15, ty = tid >> 4;
  float acc[8][8];
#pragma unroll
  for (int a = 0; a < 8; a++)
#pragma unroll
    for (int b = 0; b < 8; b++) acc[a][b] = 0.f;
  const float* ip = Is + tx * 8;
  const float* wp = Bs + ty * 8;
#pragma unroll 2
  for (int k = 0; k < 64; k++) {
    float4 iv0 = *(const float4*)(ip + k * ST_P);
    float4 iv1 = *(const float4*)(ip + k * ST_P + 4);
    float4 wv0 = *(const float4*)(wp + k * 128);
    float4 wv1 = *(const float4*)(wp + k * 128 + 4);
    float iv[8] = {iv0.x, iv0.y, iv0.z, iv0.w, iv1.x, iv1.y, iv1.z, iv1.w};
    float wv[8] = {wv0.x, wv0.y, wv0.z, wv0.w, wv1.x, wv1.y, wv1.z, wv1.w};
#pragma unroll
    for (int a = 0; a < 8; a++)
#pragma unroll
      for (int b = 0; b < 8; b++) acc[a][b] += iv[a] * wv[b];
  }
  int ibase = i0 + tx * 8;
  int o0 = ty * 8;
  float* dst = (o0 < 64) ? G : T;
  int oc = o0 & 63;
#pragma unroll
  for (int a = 0; a < 8; a++) {
    int it = ibase + a;
    if (it < N_ITEMS) {
      float4 s0 = make_float4(acc[a][0], acc[a][1], acc[a][2], acc[a][3]);
      float4 s1 = make_float4(acc[a][4], acc[a][5], acc[a][6], acc[a][7]);
      *(float4*)(dst + (size_t)it * 64 + oc) = s0;
      *(float4*)(dst + (size_t)it * 64 + oc + 4) = s1;
    }
  }
}

// ---------------- z + fuse: one wave per item --------------------------------
__global__ __launch_bounds__(256) void k_zf(const float* __restrict__ G,
                                            const float* __restrict__ T,
                                            const int* __restrict__ bins,
                                            const float* __restrict__ hp,
                                            const float* __restrict__ pp1,
                                            const float* __restrict__ gb1,
                                            const float* __restrict__ gW2,
                                            const float* __restrict__ gb2,
                                            const float* __restrict__ ib1,
                                            float* __restrict__ H1) {
  int item = blockIdx.x * 4 + (threadIdx.x >> 6);
  if (item >= N_ITEMS) return;
  int lane = threadIdx.x & 63;
  int bin = bins[item];
  float g = G[(size_t)item * 64 + lane];
  float t = T[(size_t)item * 64 + lane];
  float v = g + hp[bin * 64 + lane] + gb1[lane];
  v = (v > 0.f ? v : 0.f) * gW2[lane];
#pragma unroll
  for (int off = 32; off > 0; off >>= 1) v += __shfl_xor(v, off, 64);
  float z = 1.f / (1.f + expf(-(v + gb2[0])));
  float h = (1.f - z) * t + z * pp1[bin * 64 + lane] + ib1[lane];
  H1[(size_t)item * 64 + lane] = h > 0.f ? h : 0.f;
}

// ---------------- GEMM2: I = H1 @ iW2 + ib2  (128x64 tile, K=64) ------------
__global__ __launch_bounds__(256) void k_gemm2(const float* __restrict__ H1,
                                               const float* __restrict__ iW2,
                                               const float* __restrict__ ib2,
                                               float* __restrict__ I) {
  __shared__ float Is[64 * ST_P];
  __shared__ float Bs[64 * 64];
  int tid = threadIdx.x;
  int i0 = blockIdx.x * 128;
  {
    int c4 = tid & 15, r0 = tid >> 4;
#pragma unroll
    for (int s = 0; s < 8; s++) {
      int r = r0 + s * 16;
      int it = i0 + r;
      float4 v = make_float4(0.f, 0.f, 0.f, 0.f);
      if (it < N_ITEMS) v = *(const float4*)(H1 + (size_t)it * 64 + c4 * 4);
      Is[(c4 * 4 + 0) * ST_P + r] = v.x;
      Is[(c4 * 4 + 1) * ST_P + r] = v.y;
      Is[(c4 * 4 + 2) * ST_P + r] = v.z;
      Is[(c4 * 4 + 3) * ST_P + r] = v.w;
    }
  }
  for (int idx = tid; idx < 64 * 64; idx += 256) Bs[idx] = iW2[idx];
  __syncthreads();
  int tx = tid & 15, ty = tid >> 4;
  float acc[8][4];
#pragma unroll
  for (int a = 0; a < 8; a++)
#pragma unroll
    for (int b = 0; b < 4; b++) acc[a][b] = 0.f;
  const float* ip = Is + tx * 8;
  const float* wp = Bs + ty * 4;
#pragma unroll 2
  for (int k = 0; k < 64; k++) {
    float4 iv0 = *(const float4*)(ip + k * ST_P);
    float4 iv1 = *(const float4*)(ip + k * ST_P + 4);
    float4 wv = *(const float4*)(wp + k * 64);
    float iv[8] = {iv0.x, iv0.y, iv0.z, iv0.w, iv1.x, iv1.y, iv1.z, iv1.w};
    float wvv[4] = {wv.x, wv.y, wv.z, wv.w};
#pragma unroll
    for (int a = 0; a < 8; a++)
#pragma unroll
      for (int b = 0; b < 4; b++) acc[a][b] += iv[a] * wvv[b];
  }
  int ibase = i0 + tx * 8;
  int oc = ty * 4;
  float b0 = ib2[oc], b1 = ib2[oc + 1], b2 = ib2[oc + 2], b3 = ib2[oc + 3];
#pragma unroll
  for (int a = 0; a < 8; a++) {
    int it = ibase + a;
    if (it < N_ITEMS) {
      float4 s0 = make_float4(acc[a][0] + b0, acc[a][1] + b1,
                              acc[a][2] + b2, acc[a][3] + b3);
      *(float4*)(I + (size_t)it * 64 + oc) = s0;
    }
  }
}

// ---------------- scores: 128x128 tile GEMM, 8x8 register blocking ----------
__global__ __launch_bounds__(256) void k_scores(const float* __restrict__ I,
                                                const float* __restrict__ Ut,
                                                const float* __restrict__ item_bias,
                                                float* __restrict__ out) {
  __shared__ float Is[64 * ST_P];
  __shared__ float Us[64 * 128];
  int tid = threadIdx.x;
  int i0 = blockIdx.x * 128;
  int ubase = blockIdx.y * 128;
  {
    int c4 = tid & 15, r0 = tid >> 4;
#pragma unroll
    for (int s = 0; s < 8; s++) {
      int r = r0 + s * 16;
      int it = i0 + r;
      float4 v = make_float4(0.f, 0.f, 0.f, 0.f);
      if (it < N_ITEMS) v = *(const float4*)(I + (size_t)it * 64 + c4 * 4);
      Is[(c4 * 4 + 0) * ST_P + r] = v.x;
      Is[(c4 * 4 + 1) * ST_P + r] = v.y;
      Is[(c4 * 4 + 2) * ST_P + r] = v.z;
      Is[(c4 * 4 + 3) * ST_P + r] = v.w;
    }
  }
  {
    int u4 = tid & 31, k0 = tid >> 5;
#pragma unroll
    for (int s = 0; s < 8; s++) {
      int k = k0 + s * 8;
      float4 v = *(const float4*)(Ut + k * 256 + ubase + u4 * 4);
      *(float4*)(Us + k * 128 + u4 * 4) = v;
    }
  }
  __syncthreads();
  int tx = tid & 15;
  int ty = tid >> 4;
  float acc[8][8];
#pragma unroll
  for (int a = 0; a < 8; a++)
#pragma unroll
    for (int b = 0; b < 8; b++) acc[a][b] = 0.f;
  const float* ip = Is + tx * 8;
  const float* up = Us + ty * 8;
#pragma unroll 2
  for (int k = 0; k < 64; k++) {
    float4 iv0 = *(const float4*)(ip + k * ST_P);
    float4 iv1 = *(const float4*)(ip + k * ST_P + 4);
    float4 uv0 = *(const float4*)(up + k * 128);
    float4 uv1 = *(const float4*)(up + k * 128 + 4);
    float iv[8] = {iv0.x, iv0.y, iv0.z, iv0.w, iv1.x, iv1.y, iv1.z, iv1.w};
    float uv[8] = {uv0.x, uv0.y, uv0.z, uv0.w, uv1.x, uv1.y, uv1.z, uv1.w};
#pragma unroll
    for (int a = 0; a < 8; a++)
#pragma unroll
      for (int b = 0; b < 8; b++) acc[a][b] += iv[a] * uv[b];
  }
  int ibase = i0 + tx * 8;
  float ib[8];
#pragma unroll
  for (int a = 0; a < 8; a++)
    ib[a] = (ibase + a < N_ITEMS) ? item_bias[ibase + a] : 0.f;
#pragma unroll
  for (int bb = 0; bb < 8; bb++) {
    int bu = ubase + ty * 8 + bb;
    float ubias = Ut[64 * 256 + bu];
    float* orow = out + (size_t)bu * N_ITEMS + ibase;
    if (ibase + 7 < N_ITEMS) {
      float4 s0 = make_float4(acc[0][bb] + ubias + ib[0], acc[1][bb] + ubias + ib[1],
                              acc[2][bb] + ubias + ib[2], acc[3][bb] + ubias + ib[3]);
      float4 s1 = make_float4(acc[4][bb] + ubias + ib[4], acc[5][bb] + ubias + ib[5],
                              acc[6][bb] + ubias + ib[6], acc[7][bb] + ubias + ib[7]);
      *(float4*)orow = s0;
      *(float4*)(orow + 4) = s1;
    } else {
#pragma unroll
      for (int a = 0; a < 8; a++)
        if (ibase + a < N_ITEMS) orow[a] = acc[a][bb] + ubias + ib[a];
    }
  }
}

extern "C" void kernel_launch(void* const* d_in, const int* in_sizes, int n_in,
                              void* d_out, int out_size, void* d_ws, size_t ws_size,
                              hipStream_t stream) {
  const float* user_emb  = (const float*)d_in[0];
  const float* item_emb  = (const float*)d_in[1];
  const float* user_bias = (const float*)d_in[2];
  const float* item_bias = (const float*)d_in[3];
  const float* pop_emb   = (const float*)d_in[4];
  const float* uW1 = (const float*)d_in[5];
  const float* ub1 = (const float*)d_in[6];
  const float* uW2 = (const float*)d_in[7];
  const float* ub2 = (const float*)d_in[8];
  const float* iW1 = (const float*)d_in[9];
  const float* ib1 = (const float*)d_in[10];
  const float* iW2 = (const float*)d_in[11];
  const float* ib2 = (const float*)d_in[12];
  const float* gW1 = (const float*)d_in[13];
  const float* gb1 = (const float*)d_in[14];
  const float* gW2 = (const float*)d_in[15];
  const float* gb2 = (const float*)d_in[16];
  const float* adj_vals = (const float*)d_in[17];
  const int* adj_rows = (const int*)d_in[18];
  const int* adj_cols = (const int*)d_in[19];
  const int* bins  = (const int*)d_in[20];
  const int* users = (const int*)d_in[21];
  float* out = (float*)d_out;

  // workspace layout (float offsets); total ~132.7 MB
  float* ws = (float*)d_ws;
  float* Oacc = ws;                    // 9,600,000
  float* bufA = ws + 9600000;          // 9,600,000 (G/T/H1 after spmm)
  float* bufB = ws + 19200000;         // 9,600,000 (gstage pre-spmm; I after)
  uint2* epack = (uint2*)(ws + 28800000);      // 2,000,000 * 8B
  int* rowptr = (int*)(ws + 32800000);         // 150,001
  float* Ut   = ws + 33130000;                 // 65*256
  float* WT   = ws + 33150000;                 // 4,096 (uW1T)
  float* hp   = ws + 33160000;                 // 640
  float* pp1  = ws + 33161000;                 // 640
  int* bcur   = (int*)(ws + 33170000);         // 293 (bcnt -> excl scan -> cursor)
  uint2* gstage = (uint2*)bufB;
  float* G  = bufA;                            // 3,200,000
  float* Tm = bufA + 3200000;                  // 3,200,000
  float* H1 = bufA + 6400000;                  // 3,200,000
  float* I  = bufB;                            // 3,200,000
  const float* uW1T = WT;

  hipMemsetAsync(bcur, 0, NB2 * sizeof(int), stream);
  k_bcount<<<P1_BLOCKS, 256, 0, stream>>>(adj_rows, bcur);
  k_bscan<<<1, 512, 0, stream>>>(bcur);
  k_p1<<<P1_BLOCKS, 256, 0, stream>>>(adj_rows, adj_cols, adj_vals, bcur, gstage);
  k_p2<<<NB2, 256, 0, stream>>>(bcur, gstage, epack, rowptr);

  k_spmm1<<<37500, 256, 0, stream>>>(rowptr, epack, user_emb, item_emb, bufB, Oacc);
  k_spmm<<<37500, 256, 0, stream>>>(rowptr, epack, bufB, bufA, Oacc);
  k_spmm<<<37500, 256, 0, stream>>>(rowptr, epack, bufA, bufB, Oacc);

  k_wt<<<16, 256, 0, stream>>>(uW1, WT);
  k_pw<<<1, 256, 0, stream>>>(pop_emb, gW1, iW1, hp, pp1);
  k_user<<<4, 64, 0, stream>>>(Oacc, users, user_bias, uW1T, ub1, uW2, ub2, Ut);
  k_gemm1<<<391, 256, 0, stream>>>(Oacc, gW1, iW1, G, Tm);
  k_zf<<<12500, 256, 0, stream>>>(G, Tm, bins, hp, pp1, gb1, gW2, gb2, ib1, H1);
  k_gemm2<<<391, 256, 0, stream>>>(H1, iW2, ib2, I);
  k_scores<<<dim3(391, 2), 256, 0, stream>>>(I, Ut, item_bias, out);
}